// Round 7
// baseline (807.813 us; speedup 1.0000x reference)
//
#include <hip/hip_runtime.h>
#include <hip/hip_fp16.h>

#define NN 100000
#define NE 3200000
#define NG 256
#define NF (NN * 64)
#define FEPS 1e-5f
#define BSH 8                       // 256 dst-nodes per bucket
#define NB ((NN + 255) >> 8)        // 391 buckets
#define CHA 8192                    // edges per block in pass A
#define NCB 5                       // src column blocks
#define SRCB 20000                  // src rows per block (slice = 2.56 MB fp16)

static inline int ceil_div(int a, int b) { return (a + b - 1) / b; }

// ---------- pass A: coarse bucket partition of edges ----------

__global__ __launch_bounds__(256) void kA_hist(const int* __restrict__ dst,
                                               int* __restrict__ bh) {
    __shared__ int lh[NB];
    int t = threadIdx.x;
    for (int b = t; b < NB; b += 256) lh[b] = 0;
    __syncthreads();
    int e0 = blockIdx.x * CHA;
    int e1 = min(e0 + CHA, NE);
    for (int i = e0 + t; i < e1; i += 256) atomicAdd(&lh[dst[i] >> BSH], 1);
    __syncthreads();
    for (int b = t; b < NB; b += 256)
        if (lh[b]) atomicAdd(&bh[b], lh[b]);
}

__global__ __launch_bounds__(512) void kA_scan(const int* __restrict__ bh,
                                               int* __restrict__ bboff,
                                               int* __restrict__ bcur,
                                               int* __restrict__ rowptr2) {
    __shared__ int s[512];
    int t = threadIdx.x;
    int v = (t < NB) ? bh[t] : 0;
    s[t] = v;
    __syncthreads();
    for (int off = 1; off < 512; off <<= 1) {
        int add = (t >= off) ? s[t - off] : 0;
        __syncthreads();
        s[t] += add;
        __syncthreads();
    }
    if (t < NB) {
        int ex = s[t] - v;
        bboff[t] = ex;
        bcur[t] = ex;
    }
    if (t == 0) {
        bboff[NB] = NE;
        rowptr2[NN * NCB] = NE;   // sentinel: end of last (dst,cb) sub-row
    }
}

__global__ __launch_bounds__(256) void kA_fill(const int* __restrict__ src,
                                               const int* __restrict__ dst,
                                               int* __restrict__ bcur,
                                               int2* __restrict__ ebuf) {
    __shared__ int lh[NB];
    __shared__ int lbase[NB];
    __shared__ int lcur[NB];
    int t = threadIdx.x;
    for (int b = t; b < NB; b += 256) lh[b] = 0;
    __syncthreads();
    int e0 = blockIdx.x * CHA;
    int e1 = min(e0 + CHA, NE);
    for (int i = e0 + t; i < e1; i += 256) atomicAdd(&lh[dst[i] >> BSH], 1);
    __syncthreads();
    for (int b = t; b < NB; b += 256) {
        int c = lh[b];
        lbase[b] = c ? atomicAdd(&bcur[b], c) : 0;
        lcur[b] = 0;
    }
    __syncthreads();
    for (int i = e0 + t; i < e1; i += 256) {
        int d = dst[i];
        int s = src[i];
        int b = d >> BSH;
        int p = atomicAdd(&lcur[b], 1);
        ebuf[lbase[b] + p] = make_int2(s, d);
    }
}

// ---------- pass B: per-bucket (dst, cblock) hist + scan + CSR fill ----------
// Produces rowptr2[node*NCB + cb] (sub-rows contiguous: cb-minor, dst-major,
// bucket regions contiguous) and cnt[node]. No global scan needed.
__global__ __launch_bounds__(256) void kB(const int2* __restrict__ ebuf,
                                          const int* __restrict__ bboff,
                                          int* __restrict__ rowptr2,
                                          int* __restrict__ csr,
                                          int* __restrict__ cnt) {
    __shared__ int h[256 * NCB];
    __shared__ int s[256];
    int b = blockIdx.x, t = threadIdx.x;
    for (int i = t; i < 256 * NCB; i += 256) h[i] = 0;
    __syncthreads();
    int st = bboff[b], en = bboff[b + 1];
    for (int i = st + t; i < en; i += 256) {
        int2 e = ebuf[i];
        int cb = e.x / SRCB;
        atomicAdd(&h[(e.y & 255) * NCB + cb], 1);
    }
    __syncthreads();
    int c0 = h[t * NCB + 0], c1 = h[t * NCB + 1], c2 = h[t * NCB + 2];
    int c3 = h[t * NCB + 3], c4 = h[t * NCB + 4];
    int tot = c0 + c1 + c2 + c3 + c4;
    s[t] = tot;
    __syncthreads();
    for (int off = 1; off < 256; off <<= 1) {
        int add = (t >= off) ? s[t - off] : 0;
        __syncthreads();
        s[t] += add;
        __syncthreads();
    }
    int ex = s[t] - tot;               // exclusive offset within bucket
    int base = bboff[b];
    int o0 = ex, o1 = o0 + c0, o2 = o1 + c1, o3 = o2 + c2, o4 = o3 + c3;
    h[t * NCB + 0] = o0; h[t * NCB + 1] = o1; h[t * NCB + 2] = o2;
    h[t * NCB + 3] = o3; h[t * NCB + 4] = o4;
    int node = (b << BSH) + t;
    if (node < NN) {
        cnt[node] = tot;
        rowptr2[node * NCB + 0] = base + o0;
        rowptr2[node * NCB + 1] = base + o1;
        rowptr2[node * NCB + 2] = base + o2;
        rowptr2[node * NCB + 3] = base + o3;
        rowptr2[node * NCB + 4] = base + o4;
    }
    __syncthreads();
    for (int i = st + t; i < en; i += 256) {
        int2 e = ebuf[i];
        int cb = e.x / SRCB;
        int pos = atomicAdd(&h[(e.y & 255) * NCB + cb], 1);
        csr[base + pos] = e.x;
    }
}

// dinv[i] = rsqrt(in_deg + 1); xs[i,:] = fp16(x[i,:] * dinv[i])
__global__ __launch_bounds__(256) void k_dinv_xs(const int* __restrict__ cnt,
                                                 const float* __restrict__ x,
                                                 float* __restrict__ dinv,
                                                 __half* __restrict__ xs) {
    int i = blockIdx.x * 256 + threadIdx.x;
    if (i >= NN) return;
    float di = rsqrtf((float)cnt[i] + 1.0f);
    dinv[i] = di;
#pragma unroll
    for (int f = 0; f < 8; ++f) xs[i * 8 + f] = __float2half(x[i * 8 + f] * di);
}

// nodes-per-graph via run-length over sorted batch
__global__ __launch_bounds__(256) void k_cnts(const int* __restrict__ batch,
                                              float* __restrict__ cnts) {
    int c = blockIdx.x * 256 + threadIdx.x;
    int n0 = c * 64;
    if (n0 >= NN) return;
    int n1 = min(n0 + 64, NN);
    int gcur = batch[n0];
    float cf = 0.f;
    for (int n = n0; n < n1; ++n) {
        int gg = batch[n];
        if (gg != gcur) {
            atomicAdd(&cnts[gcur], cf);
            cf = 0.f;
            gcur = gg;
        }
        cf += 1.f;
    }
    atomicAdd(&cnts[gcur], cf);
}

// ---------- layer 1: whole-row gather of xs + 8->64 + BN + ReLU ----------

__global__ __launch_bounds__(256) void k_gxf8(const __half2* __restrict__ xs2,
                                              const int* __restrict__ rowptr2,
                                              const float* __restrict__ dinv,
                                              const int* __restrict__ csr,
                                              const float* __restrict__ W,
                                              const float* __restrict__ b,
                                              const float* __restrict__ g,
                                              const float* __restrict__ be,
                                              const float* __restrict__ rm,
                                              const float* __restrict__ rv,
                                              __half* __restrict__ out) {
    __shared__ float Ws[512];
    int tid = threadIdx.x;
    for (int i = tid; i < 512; i += 256) Ws[i] = W[i];
    __syncthreads();
    int wave = (blockIdx.x * 256 + tid) >> 6;
    int lane = tid & 63;
    if (wave >= NN) return;
    int es = lane >> 2, q = lane & 3;
    int st = rowptr2[wave * NCB];
    int n = rowptr2[wave * NCB + NCB] - st;   // full row (sub-rows contiguous)
    float ax = 0.f, ay = 0.f;
    for (int k0 = 0; k0 < n; k0 += 16) {
        int kk = k0 + es;
        if (kk < n) {
            float2 f = __half22float2(xs2[csr[st + kk] * 4 + q]);
            ax += f.x; ay += f.y;
        }
    }
    ax += __shfl_xor(ax, 4, 64);  ay += __shfl_xor(ay, 4, 64);
    ax += __shfl_xor(ax, 8, 64);  ay += __shfl_xor(ay, 8, 64);
    ax += __shfl_xor(ax, 16, 64); ay += __shfl_xor(ay, 16, 64);
    ax += __shfl_xor(ax, 32, 64); ay += __shfl_xor(ay, 32, 64);
    float di = dinv[wave];
    float2 s2 = __half22float2(xs2[wave * 4 + q]);
    float pfx = (ax + s2.x) * di;
    float pfy = (ay + s2.y) * di;
    float scale = g[lane] * rsqrtf(rv[lane] + FEPS);
    float shift = be[lane] + (b[lane] - rm[lane]) * scale;
    float o = 0.f;
#pragma unroll
    for (int qq = 0; qq < 4; ++qq) {
        float vx = __shfl(pfx, qq, 64);
        float vy = __shfl(pfy, qq, 64);
        o = fmaf(vx, Ws[(2 * qq) * 64 + lane], o);
        o = fmaf(vy, Ws[(2 * qq + 1) * 64 + lane], o);
    }
    o = fmaxf(fmaf(o, scale, shift), 0.f);
    out[wave * 64 + lane] = __float2half(o * di);
}

// ---------- phased 64-wide layer: gather slice cb, accumulate in fp32 acc ----
// PH: 0 = first (acc = self + partial), 1 = mid (acc += partial),
//     2 = last+store (transform -> fp16 out, pre-scaled), 3 = last+pool.
// Lane (p,q): p = lane>>5, q = lane&31. Partial for feature 2q+p.
template <int PH>
__global__ __launch_bounds__(256) void k_phase(const __half2* __restrict__ Hin2,
                                               const int* __restrict__ rowptr2,
                                               int cb0,
                                               const float* __restrict__ dinv,
                                               const int* __restrict__ csr,
                                               float* __restrict__ acc,
                                               const float* __restrict__ W,
                                               const float* __restrict__ bb,
                                               const float* __restrict__ g,
                                               const float* __restrict__ be,
                                               const float* __restrict__ rm,
                                               const float* __restrict__ rv,
                                               const int* __restrict__ batch,
                                               __half* __restrict__ out,
                                               float* __restrict__ sums) {
    __shared__ float Ws[(PH >= 2) ? 4096 : 1];
    int tid = threadIdx.x;
    if (PH >= 2) {
        for (int i = tid; i < 4096; i += 256) Ws[i] = W[i];
        __syncthreads();
    }
    int wave = (blockIdx.x * 256 + tid) >> 6;
    int lane = tid & 63;
    if (wave >= NN) return;
    int p = lane >> 5;
    int q = lane & 31;
    int st = rowptr2[wave * NCB + cb0];
    int n = rowptr2[wave * NCB + cb0 + 1] - st;
    float ax = 0.f, ay = 0.f;
    int k = 0;
    while (k < n) {
        int rem = n - k;
        int chunk = rem < 64 ? rem : 64;
        int eidx = (lane < chunk) ? csr[st + k + lane] : 0;
        int j = 0;
        for (; j + 8 <= chunk; j += 8) {
            int s0 = __shfl(eidx, j + 0 + p, 64);
            int s1 = __shfl(eidx, j + 2 + p, 64);
            int s2 = __shfl(eidx, j + 4 + p, 64);
            int s3 = __shfl(eidx, j + 6 + p, 64);
            float2 f0 = __half22float2(Hin2[s0 * 32 + q]);
            float2 f1 = __half22float2(Hin2[s1 * 32 + q]);
            float2 f2 = __half22float2(Hin2[s2 * 32 + q]);
            float2 f3 = __half22float2(Hin2[s3 * 32 + q]);
            ax += (f0.x + f1.x) + (f2.x + f3.x);
            ay += (f0.y + f1.y) + (f2.y + f3.y);
        }
        for (; j + 2 <= chunk; j += 2) {
            int s = __shfl(eidx, j + p, 64);
            float2 f = __half22float2(Hin2[s * 32 + q]);
            ax += f.x; ay += f.y;
        }
        if (j < chunk) {                 // odd leftover: p==0 half only
            int s = __shfl(eidx, j, 64);
            if (p == 0) {
                float2 f = __half22float2(Hin2[s * 32 + q]);
                ax += f.x; ay += f.y;
            }
        }
        k += chunk;
    }
    ax += __shfl_xor(ax, 32, 64);        // both p-halves now hold full sums
    ay += __shfl_xor(ay, 32, 64);
    float v = p ? ay : ax;               // this lane's feature = 2q+p
    int aoff = wave * 64 + 2 * q + p;
    if (PH == 0) {
        float sf = __half2float(((const __half*)Hin2)[aoff]);  // self, pre-scaled
        acc[aoff] = v + sf;
    } else if (PH == 1) {
        acc[aoff] += v;
    } else {
        float di = dinv[wave];
        float pf = (acc[aoff] + v) * di;
        float scale = g[lane] * rsqrtf(rv[lane] + FEPS);
        float shift = be[lane] + (bb[lane] - rm[lane]) * scale;
        float o0 = 0.f, o1 = 0.f;
#pragma unroll
        for (int f = 0; f < 64; f += 2) {
            float va = __shfl(pf, (f >> 1), 64);        // feature f  (p=0,q=f/2)
            float vb = __shfl(pf, 32 + (f >> 1), 64);   // feature f+1(p=1,q=f/2)
            o0 = fmaf(va, Ws[f * 64 + lane], o0);
            o1 = fmaf(vb, Ws[(f + 1) * 64 + lane], o1);
        }
        float o = fmaxf(fmaf(o0 + o1, scale, shift), 0.f);
        if (PH == 2) {
            out[wave * 64 + lane] = __float2half(o * di);   // pre-scaled
        } else {
            atomicAdd(&sums[batch[wave] * 64 + lane], o);
        }
    }
}

// ---------- head ----------

__global__ __launch_bounds__(256) void k_head(const float* __restrict__ sums,
                                              const float* __restrict__ cnts,
                                              const float* __restrict__ Wr1,
                                              const float* __restrict__ br1,
                                              const float* __restrict__ Wr2,
                                              const float* __restrict__ br2,
                                              float* __restrict__ out) {
    int wave = (blockIdx.x * 256 + threadIdx.x) >> 6;
    int lane = threadIdx.x & 63;
    if (wave >= NG) return;
    float c = fmaxf(cnts[wave], 1.0f);
    float pooled = sums[wave * 64 + lane] / c;
    float acc = 0.f;
#pragma unroll
    for (int k = 0; k < 64; ++k)
        acc = fmaf(__shfl(pooled, k, 64), Wr1[k * 64 + lane], acc);
    float hid = fmaxf(acc + br1[lane], 0.f);
    float o0 = hid * Wr2[lane * 2 + 0];
    float o1 = hid * Wr2[lane * 2 + 1];
#pragma unroll
    for (int off = 32; off > 0; off >>= 1) {
        o0 += __shfl_xor(o0, off, 64);
        o1 += __shfl_xor(o1, off, 64);
    }
    if (lane == 0) {
        out[wave * 2 + 0] = o0 + br2[0];
        out[wave * 2 + 1] = o1 + br2[1];
    }
}

extern "C" void kernel_launch(void* const* d_in, const int* in_sizes, int n_in,
                              void* d_out, int out_size, void* d_ws, size_t ws_size,
                              hipStream_t stream) {
    const float* x   = (const float*)d_in[0];
    const int*   ei  = (const int*)d_in[1];     // [2, E]: row0=src, row1=dst
    const int*   bat = (const int*)d_in[2];
    const float* W1  = (const float*)d_in[3];
    const float* b1  = (const float*)d_in[4];
    const float* g1  = (const float*)d_in[5];
    const float* be1 = (const float*)d_in[6];
    const float* rm1 = (const float*)d_in[7];
    const float* rv1 = (const float*)d_in[8];
    const float* W2  = (const float*)d_in[9];
    const float* b2  = (const float*)d_in[10];
    const float* g2  = (const float*)d_in[11];
    const float* be2 = (const float*)d_in[12];
    const float* rm2 = (const float*)d_in[13];
    const float* rv2 = (const float*)d_in[14];
    const float* W3  = (const float*)d_in[15];
    const float* b3  = (const float*)d_in[16];
    const float* g3  = (const float*)d_in[17];
    const float* be3 = (const float*)d_in[18];
    const float* rm3 = (const float*)d_in[19];
    const float* rv3 = (const float*)d_in[20];
    const float* Wr1 = (const float*)d_in[21];
    const float* br1 = (const float*)d_in[22];
    const float* Wr2 = (const float*)d_in[23];
    const float* br2 = (const float*)d_in[24];
    float* out = (float*)d_out;

    // workspace layout (4-byte words); R1 proved ws >= ~90 MB
    int*    cnt     = (int*)d_ws;                  // NN
    int*    rowptr2 = cnt + NN;                    // NN*NCB + 1
    int*    bh      = rowptr2 + NN * NCB + 1;      // NB
    int*    bboff   = bh + NB;                     // NB+1
    int*    bcur    = bboff + NB + 1;              // NB
    float*  dinv    = (float*)(bcur + NB);         // NN
    int*    csr     = (int*)(dinv + NN);           // NE
    __half* xs      = (__half*)(csr + NE);         // NN*8 halves
    float*  sums    = (float*)(xs + NN * 8);       // NG*64
    float*  cnts    = sums + NG * 64;              // NG
    __half* A       = (__half*)(cnts + NG);        // NF halves
    __half* B       = A + NF;                      // NF halves
    float*  acc     = (float*)(B + NF);            // NF floats (25.6 MB)
    int2*   ebuf    = (int2*)acc;                  // NE int2 == NF words; dead
                                                   //  after kB, before layer 2

    const int* srcI = ei;
    const int* dstI = ei + NE;

    const int gA = ceil_div(NE, CHA);        // 391
    const int gN = ceil_div(NN, 256);        // 391
    const int gW = ceil_div(NN * 64, 256);   // 25000 wave-per-node blocks

    hipMemsetAsync(bh, 0, NB * sizeof(int), stream);
    hipMemsetAsync(sums, 0, (NG * 64 + NG) * sizeof(float), stream);

    // CSR build: bucket partition, then per-bucket (dst,cb) sub-row CSR
    kA_hist<<<gA, 256, 0, stream>>>(dstI, bh);
    kA_scan<<<1, 512, 0, stream>>>(bh, bboff, bcur, rowptr2);
    kA_fill<<<gA, 256, 0, stream>>>(srcI, dstI, bcur, ebuf);
    kB<<<NB, 256, 0, stream>>>(ebuf, bboff, rowptr2, csr, cnt);
    k_dinv_xs<<<gN, 256, 0, stream>>>(cnt, x, dinv, xs);
    k_cnts<<<ceil_div(ceil_div(NN, 64), 256), 256, 0, stream>>>(bat, cnts);

    // layer 1 (whole-row; xs slice is small and L2-friendly)
    k_gxf8<<<gW, 256, 0, stream>>>((const __half2*)xs, rowptr2, dinv, csr,
                                   W1, b1, g1, be1, rm1, rv1, A);

    // layer 2: 5 column-block phases, output B (pre-scaled fp16)
    k_phase<0><<<gW, 256, 0, stream>>>((const __half2*)A, rowptr2, 0, dinv, csr, acc,
                                       W2, b2, g2, be2, rm2, rv2, bat, B, sums);
    k_phase<1><<<gW, 256, 0, stream>>>((const __half2*)A, rowptr2, 1, dinv, csr, acc,
                                       W2, b2, g2, be2, rm2, rv2, bat, B, sums);
    k_phase<1><<<gW, 256, 0, stream>>>((const __half2*)A, rowptr2, 2, dinv, csr, acc,
                                       W2, b2, g2, be2, rm2, rv2, bat, B, sums);
    k_phase<1><<<gW, 256, 0, stream>>>((const __half2*)A, rowptr2, 3, dinv, csr, acc,
                                       W2, b2, g2, be2, rm2, rv2, bat, B, sums);
    k_phase<2><<<gW, 256, 0, stream>>>((const __half2*)A, rowptr2, 4, dinv, csr, acc,
                                       W2, b2, g2, be2, rm2, rv2, bat, B, sums);

    // layer 3: same, final phase fuses mean-pool accumulation
    k_phase<0><<<gW, 256, 0, stream>>>((const __half2*)B, rowptr2, 0, dinv, csr, acc,
                                       W3, b3, g3, be3, rm3, rv3, bat, A, sums);
    k_phase<1><<<gW, 256, 0, stream>>>((const __half2*)B, rowptr2, 1, dinv, csr, acc,
                                       W3, b3, g3, be3, rm3, rv3, bat, A, sums);
    k_phase<1><<<gW, 256, 0, stream>>>((const __half2*)B, rowptr2, 2, dinv, csr, acc,
                                       W3, b3, g3, be3, rm3, rv3, bat, A, sums);
    k_phase<1><<<gW, 256, 0, stream>>>((const __half2*)B, rowptr2, 3, dinv, csr, acc,
                                       W3, b3, g3, be3, rm3, rv3, bat, A, sums);
    k_phase<3><<<gW, 256, 0, stream>>>((const __half2*)B, rowptr2, 4, dinv, csr, acc,
                                       W3, b3, g3, be3, rm3, rv3, bat, A, sums);

    k_head<<<ceil_div(NG * 64, 256), 256, 0, stream>>>(sums, cnts, Wr1, br1, Wr2, br2, out);
}